// Round 3
// baseline (797.152 us; speedup 1.0000x reference)
//
#include <hip/hip_runtime.h>

// SoftReordering: B=16, S=1024, E=1024, W=7 (fp32 in/out)
// out[b,t,e] = tanh( sum_w sigmoid(logit[b,t,w]) * win[b,t,w,e] )
// logit[b,t,v] = sum_{w,e} win[b,t,w,e] * weight[t, v, w*E+e] + bias[t,v]
// win[b,t,w,e] = x[b, t+w-3, e]  (0 if out of range)

#define Bq 16
#define Sq 1024
#define Eq 1024
#define Wq 7
#define HWq 3
#define WEq (Wq * Eq)    // 7168
#define WWEq (Wq * WEq)  // 50176

typedef float floatx4 __attribute__((ext_vector_type(4)));

// 512 threads = 8 waves per block: wave = (bg in 0..3) x (eh in 0..1).
// Each wave: 4 batches x 7 v accumulators over HALF the e range.
// Weight bytes per t unchanged vs 4-wave version (8 waves x half-tile),
// but occupancy ceiling doubles: 4 blocks/CU x 8 waves = 32 waves/CU.
__global__ __launch_bounds__(512, 8) void soft_reorder_kernel(
    const float* __restrict__ x,      // [B,S,E]
    const float* __restrict__ weight, // [S,W,W*E]
    const float* __restrict__ bias,   // [S,W]
    float* __restrict__ out)          // [B,S,E]
{
    const int bid = blockIdx.x;
    // XCD swizzle: block i -> XCD i%8; contiguous t ranges per XCD
    const int t = (bid & 7) * (Sq / 8) + (bid >> 3);
    const int tid = threadIdx.x;
    const int wid = tid >> 6;   // wave 0..7
    const int bg = wid & 3;     // batch group (4 batches)
    const int eh = wid >> 2;    // e-half (0: slots 0..127, 1: slots 128..255)
    const int ks = tid & 63;    // float4 slot within the wave's e-range

    __shared__ float red[4][2][4][28];   // [bg][eh][quarter][bi*7+v]
    __shared__ float gates[Bq][8];

    const float* wt = weight + (size_t)t * WWEq;

    // ---- Phase 1: logits (register-blocked: 4 batches x 7 v per thread) ----
    float acc[4][7];
#pragma unroll
    for (int bi = 0; bi < 4; ++bi)
#pragma unroll
        for (int v = 0; v < Wq; ++v) acc[bi][v] = 0.f;

#pragma unroll
    for (int i2 = 0; i2 < 2; ++i2) {
        const int e = (ks + (eh * 2 + i2) * 64) * 4;   // coalesced 1KB per wave-load
#pragma unroll
        for (int w = 0; w < Wq; ++w) {
            const int row = t + w - HWq;
            if ((unsigned)row < (unsigned)Sq) {
                // 7 weight float4 loads, each reused for 4 batches
                float4 wv[Wq];
#pragma unroll
                for (int v = 0; v < Wq; ++v)
                    wv[v] = *(const float4*)(wt + (size_t)v * WEq + w * Eq + e);
#pragma unroll
                for (int bi = 0; bi < 4; ++bi) {
                    const int b = bg * 4 + bi;
                    const float4 xv = *(const float4*)(x + ((size_t)b * Sq + row) * Eq + e);
#pragma unroll
                    for (int v = 0; v < Wq; ++v) {
                        acc[bi][v] = fmaf(xv.x, wv[v].x, acc[bi][v]);
                        acc[bi][v] = fmaf(xv.y, wv[v].y, acc[bi][v]);
                        acc[bi][v] = fmaf(xv.z, wv[v].z, acc[bi][v]);
                        acc[bi][v] = fmaf(xv.w, wv[v].w, acc[bi][v]);
                    }
                }
            }
        }
    }

    // Reduce over ks lanes: 4-step butterfly within 16-lane groups...
#pragma unroll
    for (int bi = 0; bi < 4; ++bi) {
#pragma unroll
        for (int v = 0; v < Wq; ++v) {
            float s = acc[bi][v];
            s += __shfl_xor(s, 1);
            s += __shfl_xor(s, 2);
            s += __shfl_xor(s, 4);
            s += __shfl_xor(s, 8);
            acc[bi][v] = s;
        }
    }
    // ...then 4 partials per wave land in LDS
    if ((ks & 15) == 0) {
        const int q = ks >> 4;  // 0..3
#pragma unroll
        for (int bi = 0; bi < 4; ++bi)
#pragma unroll
            for (int v = 0; v < Wq; ++v)
                red[bg][eh][q][bi * 7 + v] = acc[bi][v];
    }
    __syncthreads();

    // Final fold: 112 (b,v) pairs, one thread each (sum 2 e-halves x 4 quarters)
    if (tid < 4 * 28) {
        const int g = tid / 28;        // bg
        const int r = tid - g * 28;    // bi*7 + v
        const int bi = r / 7;
        const int v = r - bi * 7;
        float s = 0.f;
#pragma unroll
        for (int h = 0; h < 2; ++h)
#pragma unroll
            for (int q = 0; q < 4; ++q) s += red[g][h][q][r];
        const float logit = s + bias[t * Wq + v];
        gates[g * 4 + bi][v] = 1.0f / (1.0f + __expf(-logit));
    }
    __syncthreads();

    // ---- Phase 2: gated sum + tanh ----
    // 512 threads cover 2 full E-rows per iteration; x rows are L2-hot
    const int e2 = (tid & 255) * 4;
    const int bh = tid >> 8;   // 0 or 1
#pragma unroll 2
    for (int i = 0; i < 8; ++i) {
        const int bb = i * 2 + bh;
        float g[Wq];
#pragma unroll
        for (int w = 0; w < Wq; ++w) g[w] = gates[bb][w];

        float4 a = make_float4(0.f, 0.f, 0.f, 0.f);
#pragma unroll
        for (int w = 0; w < Wq; ++w) {
            const int row = t + w - HWq;
            if ((unsigned)row < (unsigned)Sq) {
                const float4 xv = *(const float4*)(x + ((size_t)bb * Sq + row) * Eq + e2);
                a.x += g[w] * xv.x;
                a.y += g[w] * xv.y;
                a.z += g[w] * xv.z;
                a.w += g[w] * xv.w;
            }
        }
        floatx4 o;
        o.x = 1.0f - 2.0f / (1.0f + __expf(2.0f * a.x));
        o.y = 1.0f - 2.0f / (1.0f + __expf(2.0f * a.y));
        o.z = 1.0f - 2.0f / (1.0f + __expf(2.0f * a.z));
        o.w = 1.0f - 2.0f / (1.0f + __expf(2.0f * a.w));
        // write-once data: non-temporal store, keep L2 for x/weight streams
        __builtin_nontemporal_store(o, (floatx4*)(out + ((size_t)bb * Sq + t) * Eq + e2));
    }
}

extern "C" void kernel_launch(void* const* d_in, const int* in_sizes, int n_in,
                              void* d_out, int out_size, void* d_ws, size_t ws_size,
                              hipStream_t stream) {
    const float* x = (const float*)d_in[0];      // [16,1024,1024]
    const float* weight = (const float*)d_in[1]; // [1024,7,7168]
    const float* bias = (const float*)d_in[2];   // [1024,7]
    float* out = (float*)d_out;                  // [16,1024,1024]

    soft_reorder_kernel<<<Sq, 512, 0, stream>>>(x, weight, bias, out);
}

// Round 4
// 663.832 us; speedup vs baseline: 1.2008x; 1.2008x over previous
//
#include <hip/hip_runtime.h>

// SoftReordering: B=16, S=1024, E=1024, W=7 (fp32 in/out)
// out[b,t,e] = tanh( sum_w sigmoid(logit[b,t,w]) * win[b,t,w,e] )
// logit[b,t,v] = sum_{w,e} win[b,t,w,e] * weight[t, v, w*E+e] + bias[t,v]
// win[b,t,w,e] = x[b, t+w-3, e]  (0 if out of range)

#define Bq 16
#define Sq 1024
#define Eq 1024
#define Wq 7
#define HWq 3
#define WEq (Wq * Eq)    // 7168
#define WWEq (Wq * WEq)  // 50176

typedef float floatx4 __attribute__((ext_vector_type(4)));

// 512 threads = 8 waves per block: wave = (bg in 0..3) x (eh in 0..1).
// Each wave: 4 batches x 7 v accumulators over HALF the e range.
// launch_bounds(512, 6): ~85-VGPR budget. (512,8) forced 32 VGPR -> massive
// scratch spills (FETCH 932MB, WRITE 1.13GB, 3x slowdown). This inner loop
// compiles to ~64 VGPR given headroom (R1), which still allows 4 blocks/CU.
__global__ __launch_bounds__(512, 6) void soft_reorder_kernel(
    const float* __restrict__ x,      // [B,S,E]
    const float* __restrict__ weight, // [S,W,W*E]
    const float* __restrict__ bias,   // [S,W]
    float* __restrict__ out)          // [B,S,E]
{
    const int bid = blockIdx.x;
    // XCD swizzle: block i -> XCD i%8; contiguous t ranges per XCD
    const int t = (bid & 7) * (Sq / 8) + (bid >> 3);
    const int tid = threadIdx.x;
    const int wid = tid >> 6;   // wave 0..7
    const int bg = wid & 3;     // batch group (4 batches)
    const int eh = wid >> 2;    // e-half (0: slots 0..127, 1: slots 128..255)
    const int ks = tid & 63;    // float4 slot within the wave's e-range

    __shared__ float red[4][2][4][28];   // [bg][eh][quarter][bi*7+v]
    __shared__ float gates[Bq][8];

    const float* wt = weight + (size_t)t * WWEq;

    // ---- Phase 1: logits (register-blocked: 4 batches x 7 v per thread) ----
    float acc[4][7];
#pragma unroll
    for (int bi = 0; bi < 4; ++bi)
#pragma unroll
        for (int v = 0; v < Wq; ++v) acc[bi][v] = 0.f;

#pragma unroll
    for (int i2 = 0; i2 < 2; ++i2) {
        const int e = (ks + (eh * 2 + i2) * 64) * 4;   // coalesced 1KB per wave-load
#pragma unroll
        for (int w = 0; w < Wq; ++w) {
            const int row = t + w - HWq;
            if ((unsigned)row < (unsigned)Sq) {
                // 7 weight float4 loads, each reused for 4 batches
                float4 wv[Wq];
#pragma unroll
                for (int v = 0; v < Wq; ++v)
                    wv[v] = *(const float4*)(wt + (size_t)v * WEq + w * Eq + e);
#pragma unroll
                for (int bi = 0; bi < 4; ++bi) {
                    const int b = bg * 4 + bi;
                    const float4 xv = *(const float4*)(x + ((size_t)b * Sq + row) * Eq + e);
#pragma unroll
                    for (int v = 0; v < Wq; ++v) {
                        acc[bi][v] = fmaf(xv.x, wv[v].x, acc[bi][v]);
                        acc[bi][v] = fmaf(xv.y, wv[v].y, acc[bi][v]);
                        acc[bi][v] = fmaf(xv.z, wv[v].z, acc[bi][v]);
                        acc[bi][v] = fmaf(xv.w, wv[v].w, acc[bi][v]);
                    }
                }
            }
        }
    }

    // Reduce over ks lanes: 4-step butterfly within 16-lane groups...
#pragma unroll
    for (int bi = 0; bi < 4; ++bi) {
#pragma unroll
        for (int v = 0; v < Wq; ++v) {
            float s = acc[bi][v];
            s += __shfl_xor(s, 1);
            s += __shfl_xor(s, 2);
            s += __shfl_xor(s, 4);
            s += __shfl_xor(s, 8);
            acc[bi][v] = s;
        }
    }
    // ...then 4 partials per wave land in LDS
    if ((ks & 15) == 0) {
        const int q = ks >> 4;  // 0..3
#pragma unroll
        for (int bi = 0; bi < 4; ++bi)
#pragma unroll
            for (int v = 0; v < Wq; ++v)
                red[bg][eh][q][bi * 7 + v] = acc[bi][v];
    }
    __syncthreads();

    // Final fold: 112 (b,v) pairs, one thread each (sum 2 e-halves x 4 quarters)
    if (tid < 4 * 28) {
        const int g = tid / 28;        // bg
        const int r = tid - g * 28;    // bi*7 + v
        const int bi = r / 7;
        const int v = r - bi * 7;
        float s = 0.f;
#pragma unroll
        for (int h = 0; h < 2; ++h)
#pragma unroll
            for (int q = 0; q < 4; ++q) s += red[g][h][q][r];
        const float logit = s + bias[t * Wq + v];
        gates[g * 4 + bi][v] = 1.0f / (1.0f + __expf(-logit));
    }
    __syncthreads();

    // ---- Phase 2: gated sum + tanh ----
    // 512 threads cover 2 full E-rows per iteration; x rows are L2-hot
    const int e2 = (tid & 255) * 4;
    const int bh = tid >> 8;   // 0 or 1
#pragma unroll 2
    for (int i = 0; i < 8; ++i) {
        const int bb = i * 2 + bh;
        float g[Wq];
#pragma unroll
        for (int w = 0; w < Wq; ++w) g[w] = gates[bb][w];

        float4 a = make_float4(0.f, 0.f, 0.f, 0.f);
#pragma unroll
        for (int w = 0; w < Wq; ++w) {
            const int row = t + w - HWq;
            if ((unsigned)row < (unsigned)Sq) {
                const float4 xv = *(const float4*)(x + ((size_t)bb * Sq + row) * Eq + e2);
                a.x += g[w] * xv.x;
                a.y += g[w] * xv.y;
                a.z += g[w] * xv.z;
                a.w += g[w] * xv.w;
            }
        }
        floatx4 o;
        o.x = 1.0f - 2.0f / (1.0f + __expf(2.0f * a.x));
        o.y = 1.0f - 2.0f / (1.0f + __expf(2.0f * a.y));
        o.z = 1.0f - 2.0f / (1.0f + __expf(2.0f * a.z));
        o.w = 1.0f - 2.0f / (1.0f + __expf(2.0f * a.w));
        // write-once data: non-temporal store, keep L2 for x/weight streams
        __builtin_nontemporal_store(o, (floatx4*)(out + ((size_t)bb * Sq + t) * Eq + e2));
    }
}

extern "C" void kernel_launch(void* const* d_in, const int* in_sizes, int n_in,
                              void* d_out, int out_size, void* d_ws, size_t ws_size,
                              hipStream_t stream) {
    const float* x = (const float*)d_in[0];      // [16,1024,1024]
    const float* weight = (const float*)d_in[1]; // [1024,7,7168]
    const float* bias = (const float*)d_in[2];   // [1024,7]
    float* out = (float*)d_out;                  // [16,1024,1024]

    soft_reorder_kernel<<<Sq, 512, 0, stream>>>(x, weight, bias, out);
}

// Round 5
// 387.722 us; speedup vs baseline: 2.0560x; 1.7121x over previous
//
#include <hip/hip_runtime.h>

// SoftReordering: B=16, S=1024, E=1024, W=7 (fp32 in/out)
// out[b,t,e] = tanh( sum_w sigmoid(logit[b,t,w]) * win[b,t,w,e] )
// logit[b,t,v] = sum_{w,e} win[b,t,w,e] * weight[t, v, w*E+e] + bias[t,v]
// win[b,t,w,e] = x[b, t+w-3, e]  (0 if out of range)

#define Bq 16
#define Sq 1024
#define Eq 1024
#define Wq 7
#define HWq 3
#define WEq (Wq * Eq)    // 7168
#define WWEq (Wq * WEq)  // 50176

typedef float floatx4 __attribute__((ext_vector_type(4)));

// 512 threads = 8 waves per block: wave = (bg in 0..3) x (eh in 0..1).
// Each wave: 4 batches x 7 v accumulators over HALF the e range.
// __launch_bounds__ 2nd arg behaves as min BLOCKS/CU on this toolchain:
//   (512,8) -> 32 VGPR (spill storm), (512,6) -> 40 VGPR (still spills).
// (512,2) -> 128-VGPR budget; loop naturally uses ~64 VGPR -> no spill,
// and 64 VGPR still permits 8 waves/SIMD at runtime (occupancy from usage,
// not from the bound). Grid 1024 x 8 waves = 8192 = 100% of wave slots.
__global__ __launch_bounds__(512, 2) void soft_reorder_kernel(
    const float* __restrict__ x,      // [B,S,E]
    const float* __restrict__ weight, // [S,W,W*E]
    const float* __restrict__ bias,   // [S,W]
    float* __restrict__ out)          // [B,S,E]
{
    const int bid = blockIdx.x;
    // XCD swizzle: block i -> XCD i%8; contiguous t ranges per XCD
    const int t = (bid & 7) * (Sq / 8) + (bid >> 3);
    const int tid = threadIdx.x;
    const int wid = tid >> 6;   // wave 0..7
    const int bg = wid & 3;     // batch group (4 batches)
    const int eh = wid >> 2;    // e-half (0: slots 0..127, 1: slots 128..255)
    const int ks = tid & 63;    // float4 slot within the wave's e-range

    __shared__ float red[4][2][4][28];   // [bg][eh][quarter][bi*7+v]
    __shared__ float gates[Bq][8];

    const float* wt = weight + (size_t)t * WWEq;

    // ---- Phase 1: logits (register-blocked: 4 batches x 7 v per thread) ----
    float acc[4][7];
#pragma unroll
    for (int bi = 0; bi < 4; ++bi)
#pragma unroll
        for (int v = 0; v < Wq; ++v) acc[bi][v] = 0.f;

#pragma unroll
    for (int i2 = 0; i2 < 2; ++i2) {
        const int e = (ks + (eh * 2 + i2) * 64) * 4;   // coalesced 1KB per wave-load
#pragma unroll
        for (int w = 0; w < Wq; ++w) {
            const int row = t + w - HWq;
            if ((unsigned)row < (unsigned)Sq) {
                // 7 weight float4 loads, each reused for 4 batches
                float4 wv[Wq];
#pragma unroll
                for (int v = 0; v < Wq; ++v)
                    wv[v] = *(const float4*)(wt + (size_t)v * WEq + w * Eq + e);
#pragma unroll
                for (int bi = 0; bi < 4; ++bi) {
                    const int b = bg * 4 + bi;
                    const float4 xv = *(const float4*)(x + ((size_t)b * Sq + row) * Eq + e);
#pragma unroll
                    for (int v = 0; v < Wq; ++v) {
                        acc[bi][v] = fmaf(xv.x, wv[v].x, acc[bi][v]);
                        acc[bi][v] = fmaf(xv.y, wv[v].y, acc[bi][v]);
                        acc[bi][v] = fmaf(xv.z, wv[v].z, acc[bi][v]);
                        acc[bi][v] = fmaf(xv.w, wv[v].w, acc[bi][v]);
                    }
                }
            }
        }
    }

    // Reduce over ks lanes: 4-step butterfly within 16-lane groups...
#pragma unroll
    for (int bi = 0; bi < 4; ++bi) {
#pragma unroll
        for (int v = 0; v < Wq; ++v) {
            float s = acc[bi][v];
            s += __shfl_xor(s, 1);
            s += __shfl_xor(s, 2);
            s += __shfl_xor(s, 4);
            s += __shfl_xor(s, 8);
            acc[bi][v] = s;
        }
    }
    // ...then 4 partials per wave land in LDS
    if ((ks & 15) == 0) {
        const int q = ks >> 4;  // 0..3
#pragma unroll
        for (int bi = 0; bi < 4; ++bi)
#pragma unroll
            for (int v = 0; v < Wq; ++v)
                red[bg][eh][q][bi * 7 + v] = acc[bi][v];
    }
    __syncthreads();

    // Final fold: 112 (b,v) pairs, one thread each (sum 2 e-halves x 4 quarters)
    if (tid < 4 * 28) {
        const int g = tid / 28;        // bg
        const int r = tid - g * 28;    // bi*7 + v
        const int bi = r / 7;
        const int v = r - bi * 7;
        float s = 0.f;
#pragma unroll
        for (int h = 0; h < 2; ++h)
#pragma unroll
            for (int q = 0; q < 4; ++q) s += red[g][h][q][r];
        const float logit = s + bias[t * Wq + v];
        gates[g * 4 + bi][v] = 1.0f / (1.0f + __expf(-logit));
    }
    __syncthreads();

    // ---- Phase 2: gated sum + tanh ----
    // 512 threads cover 2 full E-rows per iteration; x rows are L2-hot
    const int e2 = (tid & 255) * 4;
    const int bh = tid >> 8;   // 0 or 1
#pragma unroll 2
    for (int i = 0; i < 8; ++i) {
        const int bb = i * 2 + bh;
        float g[Wq];
#pragma unroll
        for (int w = 0; w < Wq; ++w) g[w] = gates[bb][w];

        float4 a = make_float4(0.f, 0.f, 0.f, 0.f);
#pragma unroll
        for (int w = 0; w < Wq; ++w) {
            const int row = t + w - HWq;
            if ((unsigned)row < (unsigned)Sq) {
                const float4 xv = *(const float4*)(x + ((size_t)bb * Sq + row) * Eq + e2);
                a.x += g[w] * xv.x;
                a.y += g[w] * xv.y;
                a.z += g[w] * xv.z;
                a.w += g[w] * xv.w;
            }
        }
        floatx4 o;
        o.x = 1.0f - 2.0f / (1.0f + __expf(2.0f * a.x));
        o.y = 1.0f - 2.0f / (1.0f + __expf(2.0f * a.y));
        o.z = 1.0f - 2.0f / (1.0f + __expf(2.0f * a.z));
        o.w = 1.0f - 2.0f / (1.0f + __expf(2.0f * a.w));
        // write-once data: non-temporal store, keep L2 for x/weight streams
        __builtin_nontemporal_store(o, (floatx4*)(out + ((size_t)bb * Sq + t) * Eq + e2));
    }
}

extern "C" void kernel_launch(void* const* d_in, const int* in_sizes, int n_in,
                              void* d_out, int out_size, void* d_ws, size_t ws_size,
                              hipStream_t stream) {
    const float* x = (const float*)d_in[0];      // [16,1024,1024]
    const float* weight = (const float*)d_in[1]; // [1024,7,7168]
    const float* bias = (const float*)d_in[2];   // [1024,7]
    float* out = (float*)d_out;                  // [16,1024,1024]

    soft_reorder_kernel<<<Sq, 512, 0, stream>>>(x, weight, bias, out);
}